// Round 12
// baseline (252.872 us; speedup 1.0000x reference)
//
#include <hip/hip_runtime.h>
#include <hip/hip_bf16.h>

static constexpr int NN = 50000;
static constexpr int NE = 800000;
static constexpr float BN_EPS = 1e-5f;

static constexpr int NB  = 128;    // dst buckets
static constexpr int NPB = 391;    // nodes per bucket
static constexpr int CAP = 8192;   // tmp slots per bucket
static constexpr int CHUNK = 2048;
static constexpr int SRNG = 12500; // src-range width (gather L2 locality)

typedef short bf16x8 __attribute__((ext_vector_type(8)));
typedef float f32x4 __attribute__((ext_vector_type(4)));

__device__ __forceinline__ float bflo(unsigned u) { return __uint_as_float(u << 16); }
__device__ __forceinline__ float bfhi(unsigned u) { return __uint_as_float(u & 0xffff0000u); }
__device__ __forceinline__ unsigned short f2bf(float f) {
    unsigned u = __float_as_uint(f);
    unsigned r = (u + 0x7fffu + ((u >> 16) & 1u)) >> 16;
    return (unsigned short)r;
}

// ===========================================================================
// zero
// ===========================================================================
__global__ __launch_bounds__(256) void zero_kernel(int* __restrict__ ptr, int n)
{
    int i = blockIdx.x * 256 + threadIdx.x;
    if (i < n) ptr[i] = 0;
}

// ===========================================================================
// binA: LDS-bin edges by dst bucket into fixed-cap bucket-major tmp (u32)
// ===========================================================================
__global__ __launch_bounds__(256) void binA_kernel(
    const int* __restrict__ src, const int* __restrict__ dst,
    int* __restrict__ gcount, unsigned* __restrict__ tmp)
{
    __shared__ unsigned stage[CHUNK];
    __shared__ int hist[NB], base[NB], gpos[NB];

    const int t = threadIdx.x;
    const int cb = blockIdx.x * CHUNK;
    const int total = min(CHUNK, NE - cb);

    if (t < NB) hist[t] = 0;
    __syncthreads();

    int mb[8], mslot[8];
    unsigned mv[8];
    #pragma unroll
    for (int k = 0; k < 8; ++k) {
        int e = cb + k * 256 + t;
        mb[k] = -1;
        if (e < NE) {
            int s = src[e];
            int d = dst[e];
            int b = d / NPB;
            mb[k] = b;
            mv[k] = ((unsigned)d << 16) | (unsigned)s;
            mslot[k] = atomicAdd(&hist[b], 1);
        }
    }
    __syncthreads();

    if (t < NB) base[t] = hist[t];
    __syncthreads();
    for (int ofs = 1; ofs < NB; ofs <<= 1) {
        int v = (t >= ofs && t < NB) ? base[t - ofs] : 0;
        __syncthreads();
        if (t < NB) base[t] += v;
        __syncthreads();
    }
    if (t < NB && hist[t] > 0)
        gpos[t] = t * CAP + atomicAdd(&gcount[t], hist[t]);
    __syncthreads();

    #pragma unroll
    for (int k = 0; k < 8; ++k) {
        if (mb[k] >= 0) {
            int b = mb[k];
            stage[(base[b] - hist[b]) + mslot[k]] = mv[k];
        }
    }
    __syncthreads();

    for (int i = t; i < total; i += 256) {
        unsigned v = stage[i];
        int b = (int)(v >> 16) / NPB;
        int pos = gpos[b] + (i - (base[b] - hist[b]));
        tmp[pos] = v;
    }
}

// ===========================================================================
// binB: per bucket: per-(node,src-range) hist + scan -> off + src-ordered eidx
// ===========================================================================
__global__ __launch_bounds__(256) void binB_kernel(
    const unsigned* __restrict__ tmp, const int* __restrict__ gcount,
    int* __restrict__ off, int* __restrict__ eidx)
{
    __shared__ int gb[NB];
    __shared__ int hist4[NPB * 4];
    __shared__ int hs[512];
    __shared__ int cur4[NPB * 4];
    __shared__ int base_s;

    const int t = threadIdx.x;
    const int b = blockIdx.x;
    const int n0 = b * NPB;
    const int n1 = min(n0 + NPB, NN);
    const int nnodes = n1 - n0;
    const int cnt = gcount[b];

    if (t < NB) gb[t] = gcount[t];
    for (int i = t; i < NPB * 4; i += 256) hist4[i] = 0;
    __syncthreads();
    for (int ofs = 1; ofs < NB; ofs <<= 1) {
        int v = (t >= ofs && t < NB) ? gb[t - ofs] : 0;
        __syncthreads();
        if (t < NB) gb[t] += v;
        __syncthreads();
    }
    if (t == 0) base_s = (b == 0) ? 0 : gb[b - 1];
    __syncthreads();
    const int base = base_s;

    const unsigned* tb = tmp + (size_t)b * CAP;
    for (int i = t; i < cnt; i += 256) {
        unsigned v = tb[i];
        int d = (int)(v >> 16);
        int s = (int)(v & 0xffffu);
        atomicAdd(&hist4[(d - n0) * 4 + s / SRNG], 1);
    }
    __syncthreads();
    {
        int n = t;
        hs[t] = (n < NPB) ? (hist4[n * 4] + hist4[n * 4 + 1] +
                             hist4[n * 4 + 2] + hist4[n * 4 + 3]) : 0;
        n = t + 256;
        hs[t + 256] = (n < NPB) ? (hist4[n * 4] + hist4[n * 4 + 1] +
                                   hist4[n * 4 + 2] + hist4[n * 4 + 3]) : 0;
    }
    __syncthreads();
    for (int ofs = 1; ofs < 512; ofs <<= 1) {
        int a0 = (t >= ofs) ? hs[t - ofs] : 0;
        int a1 = hs[t + 256 - ofs];
        __syncthreads();
        hs[t] += a0;
        hs[t + 256] += a1;
        __syncthreads();
    }
    for (int n = t; n < nnodes; n += 256) {
        int h0 = hist4[n * 4], h1 = hist4[n * 4 + 1], h2 = hist4[n * 4 + 2];
        int tot = h0 + h1 + h2 + hist4[n * 4 + 3];
        int c = base + hs[n] - tot;
        off[n0 + n] = c;
        cur4[n * 4 + 0] = c; c += h0;
        cur4[n * 4 + 1] = c; c += h1;
        cur4[n * 4 + 2] = c; c += h2;
        cur4[n * 4 + 3] = c;
    }
    if (b == NB - 1 && t == 0) off[NN] = base + cnt;
    __syncthreads();
    for (int i = t; i < cnt; i += 256) {
        unsigned v = tb[i];
        int d = (int)(v >> 16);
        int s = (int)(v & 0xffffu);
        int pos = atomicAdd(&cur4[(d - n0) * 4 + s / SRNG], 1);
        eidx[pos] = s;
    }
}

// ===========================================================================
// proj0 (layer 0 only): p(bf16) = h(fp32) @ W1. 128 rows/block, fp32 4x8 tile.
// ===========================================================================
__global__ __launch_bounds__(256) void proj0_kernel(
    const float* __restrict__ hin, const float* __restrict__ W1,
    unsigned short* __restrict__ p)
{
    constexpr int D = 128;
    constexpr int RPB = 128;
    __shared__ float XsT[64][132];
    __shared__ float Ws[64][64];

    const int t = threadIdx.x;
    const int rowbase = blockIdx.x * RPB;

    const int tc = t & 7;
    const int tr = t >> 3;
    const int c0 = tc * 8;
    const int r0 = tr * 4;

    float acc[4][8];
    #pragma unroll
    for (int i = 0; i < 4; ++i)
        #pragma unroll
        for (int j = 0; j < 8; ++j) acc[i][j] = 0.f;

    for (int kc = 0; kc < D; kc += 64) {
        if (kc) __syncthreads();
        {
            const float4* wg = reinterpret_cast<const float4*>(W1 + (size_t)kc * 64);
            float4* wl = reinterpret_cast<float4*>(&Ws[0][0]);
            for (int i = t; i < 64 * 16; i += 256) wl[i] = wg[i];
        }
        {
            int rr = t & 15, q = t >> 4;
            for (int i = 0; i < RPB; i += 16) {
                int r = i + rr;
                int gr = rowbase + r;
                float4 v = make_float4(0.f, 0.f, 0.f, 0.f);
                if (gr < NN)
                    v = reinterpret_cast<const float4*>(hin + (size_t)gr * D + kc)[q];
                XsT[q * 4 + 0][r] = v.x;
                XsT[q * 4 + 1][r] = v.y;
                XsT[q * 4 + 2][r] = v.z;
                XsT[q * 4 + 3][r] = v.w;
            }
        }
        __syncthreads();

        for (int k = 0; k < 64; ++k) {
            float4 xa = *reinterpret_cast<const float4*>(&XsT[k][r0]);
            float4 wa = *reinterpret_cast<const float4*>(&Ws[k][c0]);
            float4 wb = *reinterpret_cast<const float4*>(&Ws[k][c0 + 4]);
            float x[4] = { xa.x, xa.y, xa.z, xa.w };
            float w[8] = { wa.x, wa.y, wa.z, wa.w, wb.x, wb.y, wb.z, wb.w };
            #pragma unroll
            for (int i = 0; i < 4; ++i)
                #pragma unroll
                for (int j = 0; j < 8; ++j) acc[i][j] += x[i] * w[j];
        }
    }

    #pragma unroll
    for (int i = 0; i < 4; ++i) {
        int gr = rowbase + r0 + i;
        if (gr < NN) {
            uint4 u;
            u.x = (unsigned)f2bf(acc[i][0]) | ((unsigned)f2bf(acc[i][1]) << 16);
            u.y = (unsigned)f2bf(acc[i][2]) | ((unsigned)f2bf(acc[i][3]) << 16);
            u.z = (unsigned)f2bf(acc[i][4]) | ((unsigned)f2bf(acc[i][5]) << 16);
            u.w = (unsigned)f2bf(acc[i][6]) | ((unsigned)f2bf(acc[i][7]) << 16);
            *reinterpret_cast<uint4*>(p + (size_t)gr * 64 + c0) = u;
        }
    }
}

// ===========================================================================
// proj_mfma: p(bf16) = relu(zb*scale+shift) @ W1  (layers 1-3)
// 64 rows/block, 4 waves; wave w -> rows w*16..+15; MFMA 16x16x32 bf16.
// A/B k-mapping: k = 8*(lane>>4) + elem (consistent on both operands).
// ===========================================================================
__global__ __launch_bounds__(256) void proj_mfma(
    const unsigned short* __restrict__ zbin, const float* __restrict__ W1,
    const float* __restrict__ gsum, const float* __restrict__ gsq,
    const float* __restrict__ gamma, const float* __restrict__ beta,
    unsigned short* __restrict__ p)
{
    __shared__ unsigned short Wt[64][72];   // Wt[c][k], pad->uniform banks
    __shared__ float scs[64], shs[64];

    const int t = threadIdx.x;
    if (t < 64) {
        const float invn = 1.f / (float)NN;
        float mean = gsum[t] * invn;
        float var  = gsq[t] * invn - mean * mean;
        float sc   = gamma[t] * rsqrtf(var + BN_EPS);
        scs[t] = sc;
        shs[t] = beta[t] - mean * sc;
    }
    for (int i = t; i < 64 * 16; i += 256) {
        int k = i >> 4, c0 = (i & 15) * 4;
        float4 w = *reinterpret_cast<const float4*>(W1 + (size_t)k * 64 + c0);
        Wt[c0 + 0][k] = f2bf(w.x); Wt[c0 + 1][k] = f2bf(w.y);
        Wt[c0 + 2][k] = f2bf(w.z); Wt[c0 + 3][k] = f2bf(w.w);
    }
    __syncthreads();

    const int wv = t >> 6;
    const int l = t & 63;
    const int g = l >> 4;
    const int cl = l & 15;
    const int rowbase = blockIdx.x * 64 + wv * 16;

    // A frags: row = rowbase+cl, k = 8g+e (+32 for second)
    int ar = min(rowbase + cl, NN - 1);
    const unsigned short* yrow = zbin + (size_t)ar * 64;
    bf16x8 a0, a1;
    {
        uint4 u0 = *reinterpret_cast<const uint4*>(yrow + 8 * g);
        uint4 u1 = *reinterpret_cast<const uint4*>(yrow + 32 + 8 * g);
        unsigned uu[8] = { u0.x, u0.y, u0.z, u0.w, u1.x, u1.y, u1.z, u1.w };
        unsigned short oo[16];
        #pragma unroll
        for (int q = 0; q < 8; ++q) {
            int kb = (q < 4) ? (8 * g + q * 2) : (32 + 8 * g + (q - 4) * 2);
            float f0 = bflo(uu[q]), f1 = bfhi(uu[q]);
            oo[q * 2 + 0] = f2bf(fmaxf(f0 * scs[kb + 0] + shs[kb + 0], 0.f));
            oo[q * 2 + 1] = f2bf(fmaxf(f1 * scs[kb + 1] + shs[kb + 1], 0.f));
        }
        a0 = *reinterpret_cast<bf16x8*>(&oo[0]);
        a1 = *reinterpret_cast<bf16x8*>(&oo[8]);
    }

    f32x4 acc[4];
    #pragma unroll
    for (int ct = 0; ct < 4; ++ct) acc[ct] = (f32x4){0.f, 0.f, 0.f, 0.f};

    #pragma unroll
    for (int ct = 0; ct < 4; ++ct) {
        bf16x8 b0 = *reinterpret_cast<const bf16x8*>(&Wt[ct * 16 + cl][8 * g]);
        bf16x8 b1 = *reinterpret_cast<const bf16x8*>(&Wt[ct * 16 + cl][32 + 8 * g]);
        acc[ct] = __builtin_amdgcn_mfma_f32_16x16x32_bf16(a0, b0, acc[ct], 0, 0, 0);
        acc[ct] = __builtin_amdgcn_mfma_f32_16x16x32_bf16(a1, b1, acc[ct], 0, 0, 0);
    }

    // D: col = ct*16+cl, row = rowbase + 4g + j
    #pragma unroll
    for (int ct = 0; ct < 4; ++ct) {
        int col = ct * 16 + cl;
        #pragma unroll
        for (int j = 0; j < 4; ++j) {
            int gr = rowbase + 4 * g + j;
            if (gr < NN) p[(size_t)gr * 64 + col] = f2bf(acc[ct][j]);
        }
    }
}

// ===========================================================================
// mlp2_mfma: z(bf16) = Y(bf16) @ W2 + b2, BN stats fp32.  64 rows/block.
// ===========================================================================
__global__ __launch_bounds__(256) void mlp2_mfma(
    const unsigned short* __restrict__ Y, const float* __restrict__ W2,
    const float* __restrict__ b2, unsigned short* __restrict__ zb,
    float* __restrict__ gsum, float* __restrict__ gsq)
{
    __shared__ unsigned short Wt[64][72];
    __shared__ float b2s[64], lsum[64], lsq[64];

    const int t = threadIdx.x;
    if (t < 64) { b2s[t] = b2[t]; lsum[t] = 0.f; lsq[t] = 0.f; }
    for (int i = t; i < 64 * 16; i += 256) {
        int k = i >> 4, c0 = (i & 15) * 4;
        float4 w = *reinterpret_cast<const float4*>(W2 + (size_t)k * 64 + c0);
        Wt[c0 + 0][k] = f2bf(w.x); Wt[c0 + 1][k] = f2bf(w.y);
        Wt[c0 + 2][k] = f2bf(w.z); Wt[c0 + 3][k] = f2bf(w.w);
    }
    __syncthreads();

    const int wv = t >> 6;
    const int l = t & 63;
    const int g = l >> 4;
    const int cl = l & 15;
    const int rowbase = blockIdx.x * 64 + wv * 16;

    int ar = min(rowbase + cl, NN - 1);
    const unsigned short* yrow = Y + (size_t)ar * 64;
    bf16x8 a0 = *reinterpret_cast<const bf16x8*>(yrow + 8 * g);
    bf16x8 a1 = *reinterpret_cast<const bf16x8*>(yrow + 32 + 8 * g);

    f32x4 acc[4];
    #pragma unroll
    for (int ct = 0; ct < 4; ++ct) acc[ct] = (f32x4){0.f, 0.f, 0.f, 0.f};

    #pragma unroll
    for (int ct = 0; ct < 4; ++ct) {
        bf16x8 b0 = *reinterpret_cast<const bf16x8*>(&Wt[ct * 16 + cl][8 * g]);
        bf16x8 b1 = *reinterpret_cast<const bf16x8*>(&Wt[ct * 16 + cl][32 + 8 * g]);
        acc[ct] = __builtin_amdgcn_mfma_f32_16x16x32_bf16(a0, b0, acc[ct], 0, 0, 0);
        acc[ct] = __builtin_amdgcn_mfma_f32_16x16x32_bf16(a1, b1, acc[ct], 0, 0, 0);
    }

    #pragma unroll
    for (int ct = 0; ct < 4; ++ct) {
        int col = ct * 16 + cl;
        float bb = b2s[col];
        float s = 0.f, sq = 0.f;
        float zv[4];
        #pragma unroll
        for (int j = 0; j < 4; ++j) {
            int gr = rowbase + 4 * g + j;
            float z = acc[ct][j] + bb;
            zv[j] = z;
            if (gr < NN) { s += z; sq += z * z; }
        }
        s  += __shfl_xor(s, 16);  s  += __shfl_xor(s, 32);
        sq += __shfl_xor(sq, 16); sq += __shfl_xor(sq, 32);
        if (l < 16) { atomicAdd(&lsum[col], s); atomicAdd(&lsq[col], sq); }
        #pragma unroll
        for (int j = 0; j < 4; ++j) {
            int gr = rowbase + 4 * g + j;
            if (gr < NN) zb[(size_t)gr * 64 + col] = f2bf(zv[j]);
        }
    }
    __syncthreads();
    if (t < 64) { atomicAdd(&gsum[t], lsum[t]); atomicAdd(&gsq[t], lsq[t]); }
}

// ===========================================================================
// gather: Y[i] = relu(p[i] + sum_{j in N(i)} p[j] + b1)   (bf16 in/out)
// ===========================================================================
__global__ __launch_bounds__(256) void gather_kernel(
    const unsigned short* __restrict__ p, const int* __restrict__ off,
    const int* __restrict__ eidx, const float* __restrict__ b1,
    unsigned short* __restrict__ Y)
{
    int gid = blockIdx.x * 256 + threadIdx.x;
    if (gid >= NN * 8) return;
    int row = gid >> 3;
    int q = gid & 7;

    const uint4* pb = reinterpret_cast<const uint4*>(p);
    uint4 u = pb[row * 8 + q];
    float a0 = bflo(u.x), a1 = bfhi(u.x), a2 = bflo(u.y), a3 = bfhi(u.y);
    float a4 = bflo(u.z), a5 = bfhi(u.z), a6 = bflo(u.w), a7 = bfhi(u.w);

    int e = off[row];
    const int end = off[row + 1];
    for (; e + 4 <= end; e += 4) {
        int s0 = eidx[e + 0], s1 = eidx[e + 1];
        int s2 = eidx[e + 2], s3 = eidx[e + 3];
        uint4 v0 = pb[s0 * 8 + q];
        uint4 v1 = pb[s1 * 8 + q];
        uint4 v2 = pb[s2 * 8 + q];
        uint4 v3 = pb[s3 * 8 + q];
        a0 += (bflo(v0.x) + bflo(v1.x)) + (bflo(v2.x) + bflo(v3.x));
        a1 += (bfhi(v0.x) + bfhi(v1.x)) + (bfhi(v2.x) + bfhi(v3.x));
        a2 += (bflo(v0.y) + bflo(v1.y)) + (bflo(v2.y) + bflo(v3.y));
        a3 += (bfhi(v0.y) + bfhi(v1.y)) + (bfhi(v2.y) + bfhi(v3.y));
        a4 += (bflo(v0.z) + bflo(v1.z)) + (bflo(v2.z) + bflo(v3.z));
        a5 += (bfhi(v0.z) + bfhi(v1.z)) + (bfhi(v2.z) + bfhi(v3.z));
        a6 += (bflo(v0.w) + bflo(v1.w)) + (bflo(v2.w) + bflo(v3.w));
        a7 += (bfhi(v0.w) + bfhi(v1.w)) + (bfhi(v2.w) + bfhi(v3.w));
    }
    for (; e < end; ++e) {
        uint4 v = pb[eidx[e] * 8 + q];
        a0 += bflo(v.x); a1 += bfhi(v.x); a2 += bflo(v.y); a3 += bfhi(v.y);
        a4 += bflo(v.z); a5 += bfhi(v.z); a6 += bflo(v.w); a7 += bfhi(v.w);
    }

    float4 blo = reinterpret_cast<const float4*>(b1)[q * 2];
    float4 bhi = reinterpret_cast<const float4*>(b1)[q * 2 + 1];
    a0 = fmaxf(a0 + blo.x, 0.f); a1 = fmaxf(a1 + blo.y, 0.f);
    a2 = fmaxf(a2 + blo.z, 0.f); a3 = fmaxf(a3 + blo.w, 0.f);
    a4 = fmaxf(a4 + bhi.x, 0.f); a5 = fmaxf(a5 + bhi.y, 0.f);
    a6 = fmaxf(a6 + bhi.z, 0.f); a7 = fmaxf(a7 + bhi.w, 0.f);

    uint4 o;
    o.x = (unsigned)f2bf(a0) | ((unsigned)f2bf(a1) << 16);
    o.y = (unsigned)f2bf(a2) | ((unsigned)f2bf(a3) << 16);
    o.z = (unsigned)f2bf(a4) | ((unsigned)f2bf(a5) << 16);
    o.w = (unsigned)f2bf(a6) | ((unsigned)f2bf(a7) << 16);
    reinterpret_cast<uint4*>(Y)[row * 8 + q] = o;
}

// ===========================================================================
// final norm: out(fp32) = relu(zb*scale+shift), zb bf16
// ===========================================================================
__global__ __launch_bounds__(256) void norm_kernel(
    const unsigned short* __restrict__ zb,
    const float* __restrict__ gsum, const float* __restrict__ gsq,
    const float* __restrict__ gamma, const float* __restrict__ beta,
    float* __restrict__ out)
{
    __shared__ float sc[64], sh[64];
    int t = threadIdx.x;
    if (t < 64) {
        const float invn = 1.f / (float)NN;
        float mean = gsum[t] * invn;
        float var  = gsq[t] * invn - mean * mean;
        float s    = gamma[t] * rsqrtf(var + BN_EPS);
        sc[t] = s;
        sh[t] = beta[t] - mean * s;
    }
    __syncthreads();
    int idx = blockIdx.x * 256 + t;
    if (idx >= NN * 8) return;
    int row = idx >> 3;
    int q = idx & 7;
    int c = q * 8;
    uint4 v = reinterpret_cast<const uint4*>(zb)[idx];
    float f0 = bflo(v.x), f1 = bfhi(v.x), f2 = bflo(v.y), f3 = bfhi(v.y);
    float f4 = bflo(v.z), f5 = bfhi(v.z), f6 = bflo(v.w), f7 = bfhi(v.w);
    float4 lo, hi;
    lo.x = fmaxf(f0 * sc[c + 0] + sh[c + 0], 0.f);
    lo.y = fmaxf(f1 * sc[c + 1] + sh[c + 1], 0.f);
    lo.z = fmaxf(f2 * sc[c + 2] + sh[c + 2], 0.f);
    lo.w = fmaxf(f3 * sc[c + 3] + sh[c + 3], 0.f);
    hi.x = fmaxf(f4 * sc[c + 4] + sh[c + 4], 0.f);
    hi.y = fmaxf(f5 * sc[c + 5] + sh[c + 5], 0.f);
    hi.z = fmaxf(f6 * sc[c + 6] + sh[c + 6], 0.f);
    hi.w = fmaxf(f7 * sc[c + 7] + sh[c + 7], 0.f);
    float* o = out + (size_t)row * 64 + c;
    *reinterpret_cast<float4*>(o) = lo;
    *reinterpret_cast<float4*>(o + 4) = hi;
}

// ===========================================================================
extern "C" void kernel_launch(void* const* d_in, const int* in_sizes, int n_in,
                              void* d_out, int out_size, void* d_ws, size_t ws_size,
                              hipStream_t stream)
{
    const float* h    = (const float*)d_in[0];
    const int*   src  = (const int*)d_in[1];
    const int*   dst  = (const int*)d_in[2];
    const float* W1_0 = (const float*)d_in[3];
    const float* b1_0 = (const float*)d_in[4];
    const float* W2_0 = (const float*)d_in[5];
    const float* b2_0 = (const float*)d_in[6];
    const float* g_0  = (const float*)d_in[7];
    const float* be_0 = (const float*)d_in[8];
    const float* W1st = (const float*)d_in[9];
    const float* b1st = (const float*)d_in[10];
    const float* W2st = (const float*)d_in[11];
    const float* b2st = (const float*)d_in[12];
    const float* gst  = (const float*)d_in[13];
    const float* best = (const float*)d_in[14];
    float* out = (float*)d_out;

    char* ws = (char*)d_ws;
    unsigned short* p  = (unsigned short*)ws;                    // NN*64 bf16
    unsigned short* Y  = p + (size_t)NN * 64;                    // NN*64 bf16
    unsigned short* zb = Y + (size_t)NN * 64;                    // NN*64 bf16
    unsigned* tmp = (unsigned*)(zb + (size_t)NN * 64);           // NB*CAP u32
    int* eidx   = (int*)(tmp + (size_t)NB * CAP);                // NE
    float* stats = (float*)(eidx + NE);                          // 512 floats
    int* gcount = (int*)(stats + 512);                           // NB (adjacent)
    int* off    = gcount + NB;                                   // NN+1

    // ---- CSR build ----
    zero_kernel<<<3, 256, 0, stream>>>((int*)stats, 512 + NB);
    binA_kernel<<<(NE + CHUNK - 1) / CHUNK, 256, 0, stream>>>(src, dst, gcount, tmp);
    binB_kernel<<<NB, 256, 0, stream>>>(tmp, gcount, off, eidx);

    const int gemmblk   = (NN + 127) / 128;
    const int mfmablk   = (NN + 63) / 64;
    const int gatherblk = (NN * 8 + 255) / 256;
    const int normblk   = (NN * 8 + 255) / 256;

    float* gs0 = stats + 0 * 128;
    proj0_kernel<<<gemmblk, 256, 0, stream>>>(h, W1_0, p);
    gather_kernel<<<gatherblk, 256, 0, stream>>>(p, off, eidx, b1_0, Y);
    mlp2_mfma<<<mfmablk, 256, 0, stream>>>(Y, W2_0, b2_0, zb, gs0, gs0 + 64);

    const float* gammas[4] = { g_0, gst + 0, gst + 64, gst + 128 };
    const float* betas[4]  = { be_0, best + 0, best + 64, best + 128 };

    for (int l = 0; l < 3; ++l) {
        float* gsp = stats + l * 128;
        float* gsc = stats + (l + 1) * 128;
        proj_mfma<<<mfmablk, 256, 0, stream>>>(
            zb, W1st + l * 4096, gsp, gsp + 64, gammas[l], betas[l], p);
        gather_kernel<<<gatherblk, 256, 0, stream>>>(p, off, eidx, b1st + l * 64, Y);
        mlp2_mfma<<<mfmablk, 256, 0, stream>>>(
            Y, W2st + l * 4096, b2st + l * 64, zb, gsc, gsc + 64);
    }

    float* gs3 = stats + 3 * 128;
    norm_kernel<<<normblk, 256, 0, stream>>>(zb, gs3, gs3 + 64, gammas[3], betas[3], out);
}